// Round 8
// baseline (192.815 us; speedup 1.0000x reference)
//
#include <hip/hip_runtime.h>

typedef __bf16 bf16;
typedef __bf16 bf16x8 __attribute__((ext_vector_type(8)));
typedef float f32x4 __attribute__((ext_vector_type(4)));
typedef unsigned u32x4 __attribute__((ext_vector_type(4)));

#define MFMA16(a, b, c) __builtin_amdgcn_mfma_f32_16x16x32_bf16((a), (b), (c), 0, 0, 0)

static __device__ __forceinline__ bf16x8 ldg8(const bf16* p) {
  return *(const bf16x8*)p;
}
static __device__ __forceinline__ unsigned cvt_pk_bf16(float lo, float hi) {
  unsigned d;
  asm("v_cvt_pk_bf16_f32 %0, %1, %2" : "=v"(d) : "v"(lo), "v"(hi));
  return d;
}
static __device__ __forceinline__ void pl32_swap(unsigned& a, unsigned& b) {
  asm("v_permlane32_swap_b32 %0, %1" : "+v"(a), "+v"(b));
}
static __device__ __forceinline__ void pl16_swap(unsigned& a, unsigned& b) {
  asm("v_permlane16_swap_b32 %0, %1" : "+v"(a), "+v"(b));
}

// ===========================================================================
// Ladder: 803 -> ... -> 204 -> 197.6 -> 191.2 (r7: qkv B-direct, out 64x128
// B-direct, flash split2 = 4/CU exact). Budget at 191: flash 80.8 (~850TF,
// m97-class ceiling -- frozen), qkv ~30 (fp32 x re-read 12x + cvt staging),
// combine ~7+gap, out ~7, prep 3, gaps ~12. r8: (1) x pre-converted to
// packed bf16 Xp inside prep kernel (grid 80x16, block-uniform branch) ->
// qkv staging = r4-proven pure ldg8+ds_write, x traffic halves; (2)
// flash_combine FUSED into out_gemm A-staging (same float math + RNE cvt,
// index algebra verified: U=wave*128+mhalf*64+lane <-> (kchunk=wave, r));
// kills 1 dispatch + 8.4MB Ap write + 33.6MB Ap re-read. 4 dispatches.
// ws: no overlays, end 52,953,088 < 61.4MB.
// ===========================================================================

// ---- prep: bx<16 -> pack W (fp32 [K][N]) into P32T tiles (nt<12 Wqkv,
// else Wout); bx>=16 -> cvt x (fp32 [8192][512]) into P32 tiles Xp. ----
__global__ __launch_bounds__(256) void prep(const float* __restrict__ Wqkv,
                                            const float* __restrict__ Wout,
                                            const float* __restrict__ x,
                                            bf16* __restrict__ Wp1,
                                            bf16* __restrict__ Wp2,
                                            bf16* __restrict__ Xp) {
  __shared__ float tile[32 * 129];
  if (blockIdx.x < 16) {
    int kc = blockIdx.x, nt = blockIdx.y;
    const float* W;
    bf16* dst;
    int N, ntl;
    if (nt < 12) {
      W = Wqkv; N = 1536; ntl = nt;
      dst = Wp1 + ((size_t)ntl * 16 + kc) * 4096;
    } else {
      W = Wout; N = 512; ntl = nt - 12;
      dst = Wp2 + ((size_t)ntl * 16 + kc) * 4096;
    }
    int row = threadIdx.x >> 3;
    int c0 = (threadIdx.x & 7) * 16;
    const float* src = W + (size_t)(kc * 32 + row) * N + ntl * 128 + c0;
#pragma unroll
    for (int i = 0; i < 4; i++) {
      float4 v = *(const float4*)(src + i * 4);
      tile[row * 129 + c0 + i * 4 + 0] = v.x;
      tile[row * 129 + c0 + i * 4 + 1] = v.y;
      tile[row * 129 + c0 + i * 4 + 2] = v.z;
      tile[row * 129 + c0 + i * 4 + 3] = v.w;
    }
    __syncthreads();
#pragma unroll
    for (int half = 0; half < 2; half++) {
      int U = threadIdx.x + half * 256;
      int kchunk = U >> 7, n = U & 127;
      bf16x8 o;
#pragma unroll
      for (int j = 0; j < 8; j++) o[j] = (bf16)tile[(kchunk * 8 + j) * 129 + n];
      *(bf16x8*)&dst[U * 8] = o;
    }
  } else {
    // cvt_pack_x (r4-proven): tile(mt,kc)=128x32, addr = kchunk*1024+r*8+kk
    int mt = blockIdx.x - 16, kc = blockIdx.y;
    int r = threadIdx.x >> 1;
    int khalf = threadIdx.x & 1;
    const float* src = x + (size_t)(mt * 128 + r) * 512 + kc * 32 + khalf * 16;
    float4 v0 = *(const float4*)(src + 0);
    float4 v1 = *(const float4*)(src + 4);
    float4 v2 = *(const float4*)(src + 8);
    float4 v3 = *(const float4*)(src + 12);
    bf16* dt = Xp + ((size_t)mt * 16 + kc) * 4096;
    bf16x8 a, b;
    a[0] = (bf16)v0.x; a[1] = (bf16)v0.y; a[2] = (bf16)v0.z; a[3] = (bf16)v0.w;
    a[4] = (bf16)v1.x; a[5] = (bf16)v1.y; a[6] = (bf16)v1.z; a[7] = (bf16)v1.w;
    b[0] = (bf16)v2.x; b[1] = (bf16)v2.y; b[2] = (bf16)v2.z; b[3] = (bf16)v2.w;
    b[4] = (bf16)v3.x; b[5] = (bf16)v3.y; b[6] = (bf16)v3.z; b[7] = (bf16)v3.w;
    int kc0 = khalf * 2;
    *(bf16x8*)&dt[(kc0 + 0) * 1024 + r * 8] = a;
    *(bf16x8*)&dt[(kc0 + 1) * 1024 + r * 8] = b;
  }
}

// ---------------------------------------------------------------------------
// QKV projection, 128x128 tiles. Grid (64 mt, 12 nt): nt 0-3 Q, 4-7 K,
// 8-11 V. A staged from packed bf16 Xp (pure 2xldg8 + 2xds_write, r4-proven
// one-barrier dbuf); B-frags DIRECT coalesced ldg8 from L2-resident Wp1
// (r7-proven). Epilogue: LDS round-trip for coalesced 16B stores (r6-proven;
// Q/K rows [bh][n][d]; V transposed to [bh][nb][d][n&63]).
// Q pre-scaled by 0.125*log2e (exp2 softmax downstream).
// ---------------------------------------------------------------------------
__global__ __launch_bounds__(256, 3) void qkv_gemm(const bf16* __restrict__ Xp,
                                                   const bf16* __restrict__ Wp1,
                                                   const float* __restrict__ bqkv,
                                                   bf16* __restrict__ Q,
                                                   bf16* __restrict__ Kh,
                                                   bf16* __restrict__ Vt) {
  int mt = blockIdx.x, nt = blockIdx.y;
  int tid = threadIdx.x;
  int wave = tid >> 6, lane = tid & 63;
  int l16 = lane & 15, quad = lane >> 4;
  int wr = wave >> 1, wc = wave & 1;

  __shared__ __align__(16) bf16 SM[9216];  // A dbuf 2x4096; epilogue T 128x72

  const bf16* At = Xp + (size_t)mt * 16 * 4096;
  const bf16* Bt = Wp1 + (size_t)nt * 16 * 4096;

  bf16x8 pa0 = ldg8(At + tid * 8);
  bf16x8 pa1 = ldg8(At + 2048 + tid * 8);

  f32x4 acc[4][4] = {};
#pragma unroll 2
  for (int kc = 0; kc < 16; kc++) {
    bf16* A = SM + (kc & 1) * 4096;
    *(bf16x8*)&A[tid * 8] = pa0;
    *(bf16x8*)&A[2048 + tid * 8] = pa1;
    __syncthreads();
    if (kc < 15) {
      const bf16* an = At + (kc + 1) * 4096;
      pa0 = ldg8(an + tid * 8);
      pa1 = ldg8(an + 2048 + tid * 8);
    }
    bf16x8 af[4], bfr[4];
#pragma unroll
    for (int fi = 0; fi < 4; fi++)
      af[fi] = *(const bf16x8*)&A[(quad * 128 + wr * 64 + fi * 16 + l16) * 8];
    const bf16* Bk = Bt + kc * 4096;
#pragma unroll
    for (int fj = 0; fj < 4; fj++)
      bfr[fj] = ldg8(Bk + (quad * 128 + wc * 64 + fj * 16 + l16) * 8);
    __builtin_amdgcn_s_setprio(1);
#pragma unroll
    for (int fi = 0; fi < 4; fi++)
#pragma unroll
      for (int fj = 0; fj < 4; fj++)
        acc[fi][fj] = MFMA16(af[fi], bfr[fj], acc[fi][fj]);
    __builtin_amdgcn_s_setprio(0);
  }

  // ---- epilogue: LDS round-trip, coalesced 16B stores ----
  __syncthreads();  // all frag reads done before SM reuse
  const int TS = 72;
  int b = mt >> 5;

  if (nt < 8) {
    bool isQ = nt < 4;
    bf16* dstb = isQ ? Q : Kh;
    int hb = isQ ? nt * 2 : (nt - 4) * 2;
#pragma unroll
    for (int ph = 0; ph < 2; ph++) {
      if (wc == ph) {
#pragma unroll
        for (int fj = 0; fj < 4; fj++) {
          float bias = bqkv[nt * 128 + wc * 64 + fj * 16 + l16];
#pragma unroll
          for (int fi = 0; fi < 4; fi++)
#pragma unroll
            for (int rr = 0; rr < 4; rr++) {
              float v = acc[fi][fj][rr] + bias;
              if (isQ) v *= 0.18033688f;  // 0.125*log2e
              SM[(wr * 64 + fi * 16 + quad * 4 + rr) * TS + fj * 16 + l16] =
                  (bf16)v;
            }
        }
      }
      __syncthreads();
      int bh = b * 8 + hb + ph;
      bf16* dh = dstb + (size_t)bh * 4096 * 64 + (size_t)((mt & 31) * 128) * 64;
#pragma unroll
      for (int i = 0; i < 4; i++) {
        int U = tid + i * 256;
        int mr = U >> 3, oct = U & 7;
        bf16x8 v = ldg8(&SM[mr * TS + oct * 8]);
        *(bf16x8*)&dh[(size_t)mr * 64 + oct * 8] = v;
      }
      __syncthreads();
    }
  } else {
    int h0 = (nt - 8) * 2;
#pragma unroll
    for (int ph = 0; ph < 2; ph++) {
      if (wr == ph) {
#pragma unroll
        for (int fj = 0; fj < 4; fj++) {
          float bias = bqkv[nt * 128 + wc * 64 + fj * 16 + l16];
          int cp = wc * 64 + fj * 16 + l16;
#pragma unroll
          for (int fi = 0; fi < 4; fi++)
#pragma unroll
            for (int rr = 0; rr < 4; rr++)
              SM[cp * TS + fi * 16 + quad * 4 + rr] =
                  (bf16)(acc[fi][fj][rr] + bias);
        }
      }
      __syncthreads();
      int nb = (mt & 31) * 2 + ph;
#pragma unroll
      for (int i = 0; i < 4; i++) {
        int U = tid + i * 256;
        int cp = U >> 3, oct = U & 7;
        int h = h0 + (cp >> 6), d = cp & 63;
        int bh = b * 8 + h;
        bf16x8 v = ldg8(&SM[cp * TS + oct * 8]);
        *(bf16x8*)&Vt[(((size_t)bh * 64 + nb) * 64 + d) * 64 + oct * 8] = v;
      }
      __syncthreads();
    }
  }
}

// ---------------------------------------------------------------------------
// flash_partial (r2/r5/r7-proven, ~81us, FROZEN): grid (32 strip128, 16 bh,
// 2 half) = 1024 blocks = exactly 4/CU. 4 waves, 32 Q rows/wave, 32 KV-tiles
// of 64. Per-h2 clusters: QK(8 MFMA) -> SM -> PV+l(10 MFMA). In-reg P
// (cvt_pk+permlane), exp2, ones-MFMA rowsum. K/V dbuf, ONE barrier/tile.
// ---------------------------------------------------------------------------
__global__ __launch_bounds__(256, 4) void flash_partial(const bf16* __restrict__ Q,
                                                        const bf16* __restrict__ K,
                                                        const bf16* __restrict__ Vt,
                                                        bf16* __restrict__ Opart,
                                                        float* __restrict__ Lpart) {
  int strip = blockIdx.x, bh = blockIdx.y, half = blockIdx.z;
  int tid = threadIdx.x;
  int wave = tid >> 6, lane = tid & 63;
  int l16 = lane & 15, quad = lane >> 4;

  const bf16* Qh = Q + (size_t)bh * 4096 * 64;
  const bf16* Kg = K + ((size_t)bh * 4096 + half * 2048) * 64;
  const bf16* Vg = Vt + (size_t)bh * 64 * 4096 + (size_t)half * 2048 * 64;

  __shared__ __align__(16) bf16 Klds[2][4096];
  __shared__ __align__(16) bf16 Vlds[2][4096];

  int qbase = strip * 128 + wave * 32;
  bf16x8 aq[2][2];
#pragma unroll
  for (int mt = 0; mt < 2; mt++) {
    const bf16* qr = Qh + (size_t)(qbase + mt * 16 + l16) * 64;
    aq[mt][0] = ldg8(qr + quad * 8);
    aq[mt][1] = ldg8(qr + 32 + quad * 8);
  }

  bf16x8 ones;
#pragma unroll
  for (int i = 0; i < 8; i++) ones[i] = (bf16)1.0f;

  f32x4 o[2][4] = {};
  f32x4 acc_l[2] = {};

  int e0 = tid * 8, e1 = (256 + tid) * 8;
  int r0 = e0 >> 6, r1 = e1 >> 6;
  int u0 = r0 * 8 + (((e0 & 63) >> 3) ^ (r0 & 7));
  int u1 = r1 * 8 + (((e1 & 63) >> 3) ^ (r1 & 7));

  bf16x8 kp0 = ldg8(Kg + e0), kp1 = ldg8(Kg + e1);
  bf16x8 vp0 = ldg8(Vg + e0), vp1 = ldg8(Vg + e1);

#pragma unroll 2
  for (int t = 0; t < 32; t++) {
    int cur = t & 1;
    bf16* kl = Klds[cur];
    bf16* vl = Vlds[cur];
    *(bf16x8*)&kl[u0 * 8] = kp0;
    *(bf16x8*)&kl[u1 * 8] = kp1;
    *(bf16x8*)&vl[u0 * 8] = vp0;
    *(bf16x8*)&vl[u1 * 8] = vp1;
    __syncthreads();

    if (t < 31) {
      const bf16* kg = Kg + (size_t)(t + 1) * 4096;
      const bf16* vg = Vg + (size_t)(t + 1) * 4096;
      kp0 = ldg8(kg + e0);
      kp1 = ldg8(kg + e1);
      vp0 = ldg8(vg + e0);
      vp1 = ldg8(vg + e1);
    }

#pragma unroll
    for (int h2 = 0; h2 < 2; h2++) {
      f32x4 s[2][2] = {};
      __builtin_amdgcn_s_setprio(1);
#pragma unroll
      for (int c2 = 0; c2 < 2; c2++) {
        int n = h2 * 32 + c2 * 16 + l16;
        bf16x8 k0 = *(const bf16x8*)&kl[(n * 8 + (quad ^ (n & 7))) * 8];
        bf16x8 k1 = *(const bf16x8*)&kl[(n * 8 + ((4 + quad) ^ (n & 7))) * 8];
#pragma unroll
        for (int mt = 0; mt < 2; mt++) {
          s[mt][c2] = MFMA16(k0, aq[mt][0], s[mt][c2]);
          s[mt][c2] = MFMA16(k1, aq[mt][1], s[mt][c2]);
        }
      }
      __builtin_amdgcn_s_setprio(0);

      bf16x8 pa[2];
#pragma unroll
      for (int mt = 0; mt < 2; mt++) {
        unsigned ue[2], wo[2];
#pragma unroll
        for (int c2 = 0; c2 < 2; c2++) {
          float p0 = __builtin_amdgcn_exp2f(s[mt][c2][0]);
          float p1 = __builtin_amdgcn_exp2f(s[mt][c2][1]);
          float p2 = __builtin_amdgcn_exp2f(s[mt][c2][2]);
          float p3 = __builtin_amdgcn_exp2f(s[mt][c2][3]);
          ue[c2] = cvt_pk_bf16(p0, p1);
          wo[c2] = cvt_pk_bf16(p2, p3);
        }
        pl32_swap(ue[0], ue[1]);
        pl16_swap(ue[0], ue[1]);
        pl32_swap(wo[0], wo[1]);
        pl16_swap(wo[0], wo[1]);
        u32x4 pk = {ue[0], wo[0], ue[1], wo[1]};
        pa[mt] = __builtin_bit_cast(bf16x8, pk);
      }

      __builtin_amdgcn_s_setprio(1);
      acc_l[0] = MFMA16(pa[0], ones, acc_l[0]);
      acc_l[1] = MFMA16(pa[1], ones, acc_l[1]);
#pragma unroll
      for (int ct = 0; ct < 4; ct++) {
        int d = ct * 16 + l16;
        bf16x8 bv = *(const bf16x8*)&vl[(d * 8 + ((h2 * 4 + quad) ^ (d & 7))) * 8];
        o[0][ct] = MFMA16(pa[0], bv, o[0][ct]);
        o[1][ct] = MFMA16(pa[1], bv, o[1][ct]);
      }
      __builtin_amdgcn_s_setprio(0);
    }
  }

  size_t ub = ((size_t)half * 16 + bh) * 32 + strip;
  bf16* op = Opart + ub * 8192;
#pragma unroll
  for (int mt = 0; mt < 2; mt++) {
#pragma unroll
    for (int ct = 0; ct < 4; ct++)
#pragma unroll
      for (int r = 0; r < 4; r++)
        op[(wave * 32 + mt * 16 + quad * 4 + r) * 64 + ct * 16 + l16] =
            (bf16)o[mt][ct][r];
    if (l16 == 0) {
#pragma unroll
      for (int r = 0; r < 4; r++)
        Lpart[ub * 128 + wave * 32 + mt * 16 + quad * 4 + r] = acc_l[mt][r];
    }
  }
}

// ---------------------------------------------------------------------------
// Output projection + FUSED combine: 64x128 tiles, grid (128 mt, 4 nt) =
// 512 blocks = 2/CU. A-staging computes (o0+o1)/(l0+l1) from Opart/Lpart
// directly (combine's exact math + RNE cvt; index map U=wave*128+mhalf*64+
// lane <-> kchunk=wave, r=mhalf*64+lane). B-frags direct ldg8 from Wp2.
// ---------------------------------------------------------------------------
__global__ __launch_bounds__(256, 4) void out_gemm(const bf16* __restrict__ Opart,
                                                   const float* __restrict__ Lpart,
                                                   const bf16* __restrict__ Wp2,
                                                   const float* __restrict__ bout,
                                                   float* __restrict__ Out) {
  int mt = blockIdx.x, nt = blockIdx.y;
  int tid = threadIdx.x;
  int wave = tid >> 6, lane = tid & 63;
  int l16 = lane & 15, quad = lane >> 4;
  int mt128 = mt >> 1, mhalf = mt & 1;
  int b = mt128 >> 5, strip = mt128 & 31;
  int r = mhalf * 64 + lane;

  __shared__ __align__(16) bf16 SM[2][2048];

  const bf16* Bt = Wp2 + (size_t)nt * 16 * 4096;

  bf16x8 po0, po1;
  float pls;
  {
    int h = 0, d0 = 0;  // kc = 0
    int bh = b * 8 + h;
    size_t s0 = ((size_t)bh * 32 + strip);
    size_t s1 = (((size_t)16 + bh) * 32 + strip);
    po0 = ldg8(&Opart[s0 * 8192 + r * 64 + d0 + wave * 8]);
    po1 = ldg8(&Opart[s1 * 8192 + r * 64 + d0 + wave * 8]);
    pls = Lpart[s0 * 128 + r] + Lpart[s1 * 128 + r];
  }

  f32x4 acc[4][2] = {};
#pragma unroll 2
  for (int kc = 0; kc < 16; kc++) {
    bf16* A = SM[kc & 1];
    float rl = 1.0f / pls;
    u32x4 pk = {
        cvt_pk_bf16(((float)po0[0] + (float)po1[0]) * rl,
                    ((float)po0[1] + (float)po1[1]) * rl),
        cvt_pk_bf16(((float)po0[2] + (float)po1[2]) * rl,
                    ((float)po0[3] + (float)po1[3]) * rl),
        cvt_pk_bf16(((float)po0[4] + (float)po1[4]) * rl,
                    ((float)po0[5] + (float)po1[5]) * rl),
        cvt_pk_bf16(((float)po0[6] + (float)po1[6]) * rl,
                    ((float)po0[7] + (float)po1[7]) * rl)};
    *(bf16x8*)&A[tid * 8] = __builtin_bit_cast(bf16x8, pk);
    __syncthreads();
    if (kc < 15) {
      int kn = kc + 1;
      int h = kn >> 1, d0 = (kn & 1) * 32;
      int bh = b * 8 + h;
      size_t s0 = ((size_t)bh * 32 + strip);
      size_t s1 = (((size_t)16 + bh) * 32 + strip);
      po0 = ldg8(&Opart[s0 * 8192 + r * 64 + d0 + wave * 8]);
      po1 = ldg8(&Opart[s1 * 8192 + r * 64 + d0 + wave * 8]);
      pls = Lpart[s0 * 128 + r] + Lpart[s1 * 128 + r];
    }
    bf16x8 af[4], bfr[2];
#pragma unroll
    for (int fi = 0; fi < 4; fi++)
      af[fi] = *(const bf16x8*)&A[(quad * 64 + fi * 16 + l16) * 8];
    const bf16* Bk = Bt + kc * 4096;
#pragma unroll
    for (int fj = 0; fj < 2; fj++)
      bfr[fj] = ldg8(Bk + (quad * 128 + wave * 32 + fj * 16 + l16) * 8);
    __builtin_amdgcn_s_setprio(1);
#pragma unroll
    for (int fi = 0; fi < 4; fi++)
#pragma unroll
      for (int fj = 0; fj < 2; fj++)
        acc[fi][fj] = MFMA16(af[fi], bfr[fj], acc[fi][fj]);
    __builtin_amdgcn_s_setprio(0);
  }

#pragma unroll
  for (int fj = 0; fj < 2; fj++) {
    int c = nt * 128 + wave * 32 + fj * 16 + l16;
    float bias = bout[c];
#pragma unroll
    for (int fi = 0; fi < 4; fi++) {
#pragma unroll
      for (int rr = 0; rr < 4; rr++) {
        int m = mt * 64 + fi * 16 + quad * 4 + rr;
        Out[(size_t)m * 512 + c] = acc[fi][fj][rr] + bias;
      }
    }
  }
}

// ---------------------------------------------------------------------------
// ws layout (no overlays; end 52,953,088 < 61.4MB):
//   Q 0 (8.39M) | K 8388608 | Vt 16777216 | Wp2 25165824 (0.52M) |
//   Opart 25690112 (16.78M) | Lpart 42467328 (0.52M) | Wp1 42991616 (1.57M)
//   | Xp 44564480 (8.39M)
// ---------------------------------------------------------------------------
extern "C" void kernel_launch(void* const* d_in, const int* in_sizes, int n_in,
                              void* d_out, int out_size, void* d_ws,
                              size_t ws_size, hipStream_t stream) {
  const float* x = (const float*)d_in[0];
  const float* w_qkv = (const float*)d_in[1];
  const float* b_qkv = (const float*)d_in[2];
  const float* w_out = (const float*)d_in[3];
  const float* b_out = (const float*)d_in[4];
  float* out = (float*)d_out;

  char* ws = (char*)d_ws;
  bf16* Q = (bf16*)(ws + 0);
  bf16* K = (bf16*)(ws + 8388608);
  bf16* Vt = (bf16*)(ws + 16777216);
  bf16* Wp2 = (bf16*)(ws + 25165824);
  bf16* Opart = (bf16*)(ws + 25690112);
  float* Lpart = (float*)(ws + 42467328);
  bf16* Wp1 = (bf16*)(ws + 42991616);
  bf16* Xp = (bf16*)(ws + 44564480);

  prep<<<dim3(80, 16), 256, 0, stream>>>(w_qkv, w_out, x, Wp1, Wp2, Xp);
  qkv_gemm<<<dim3(64, 12), 256, 0, stream>>>(Xp, Wp1, b_qkv, Q, K, Vt);
  flash_partial<<<dim3(32, 16, 2), 256, 0, stream>>>(Q, K, Vt, Opart, Lpart);
  out_gemm<<<dim3(128, 4), 256, 0, stream>>>(Opart, Lpart, Wp2, b_out, out);
}

// Round 9
// 191.670 us; speedup vs baseline: 1.0060x; 1.0060x over previous
//
#include <hip/hip_runtime.h>

typedef __bf16 bf16;
typedef __bf16 bf16x8 __attribute__((ext_vector_type(8)));
typedef float f32x4 __attribute__((ext_vector_type(4)));
typedef unsigned u32x4 __attribute__((ext_vector_type(4)));

#define MFMA16(a, b, c) __builtin_amdgcn_mfma_f32_16x16x32_bf16((a), (b), (c), 0, 0, 0)

static __device__ __forceinline__ bf16x8 ldg8(const bf16* p) {
  return *(const bf16x8*)p;
}
static __device__ __forceinline__ unsigned cvt_pk_bf16(float lo, float hi) {
  unsigned d;
  asm("v_cvt_pk_bf16_f32 %0, %1, %2" : "=v"(d) : "v"(lo), "v"(hi));
  return d;
}
static __device__ __forceinline__ void pl32_swap(unsigned& a, unsigned& b) {
  asm("v_permlane32_swap_b32 %0, %1" : "+v"(a), "+v"(b));
}
static __device__ __forceinline__ void pl16_swap(unsigned& a, unsigned& b) {
  asm("v_permlane16_swap_b32 %0, %1" : "+v"(a), "+v"(b));
}

// ===========================================================================
// Ladder: 803 -> ... -> 197.6 -> 191.2 (r7) -> 192.8 (r8: Xp pre-convert +
// combine-fusion, NEUTRAL -- traffic saved but combine moved onto out_gemm's
// serial path; keeping 4-dispatch structure, delta is noise). r9: SINGLE
// change -- XCD-aware swizzle on flash (T1). Diagnosis: flash FETCH 73MB vs
// 25MB ideal = 3x K/V cross-XCD over-fetch (32 strip-blocks per (bh,half)
// round-robined over 8 XCDs). Swizzle: 1D grid 1024, swz=(i&7)*128+(i>>3),
// work order l = half + 2*strip + 64*bh -> each XCD owns 2 bh entirely
// (3MB working set < 4MB L2; Q shared across halves on-XCD). Bijective
// (1024%8==0). Predict: FETCH 73->~35MB; dur 81->74-78 if latency-coupled,
// flat if purely structure-bound (decisive for 8-phase question).
// ===========================================================================

// ---- prep: bx<16 -> pack W (fp32 [K][N]) into P32T tiles (nt<12 Wqkv,
// else Wout); bx>=16 -> cvt x (fp32 [8192][512]) into P32 tiles Xp. ----
__global__ __launch_bounds__(256) void prep(const float* __restrict__ Wqkv,
                                            const float* __restrict__ Wout,
                                            const float* __restrict__ x,
                                            bf16* __restrict__ Wp1,
                                            bf16* __restrict__ Wp2,
                                            bf16* __restrict__ Xp) {
  __shared__ float tile[32 * 129];
  if (blockIdx.x < 16) {
    int kc = blockIdx.x, nt = blockIdx.y;
    const float* W;
    bf16* dst;
    int N, ntl;
    if (nt < 12) {
      W = Wqkv; N = 1536; ntl = nt;
      dst = Wp1 + ((size_t)ntl * 16 + kc) * 4096;
    } else {
      W = Wout; N = 512; ntl = nt - 12;
      dst = Wp2 + ((size_t)ntl * 16 + kc) * 4096;
    }
    int row = threadIdx.x >> 3;
    int c0 = (threadIdx.x & 7) * 16;
    const float* src = W + (size_t)(kc * 32 + row) * N + ntl * 128 + c0;
#pragma unroll
    for (int i = 0; i < 4; i++) {
      float4 v = *(const float4*)(src + i * 4);
      tile[row * 129 + c0 + i * 4 + 0] = v.x;
      tile[row * 129 + c0 + i * 4 + 1] = v.y;
      tile[row * 129 + c0 + i * 4 + 2] = v.z;
      tile[row * 129 + c0 + i * 4 + 3] = v.w;
    }
    __syncthreads();
#pragma unroll
    for (int half = 0; half < 2; half++) {
      int U = threadIdx.x + half * 256;
      int kchunk = U >> 7, n = U & 127;
      bf16x8 o;
#pragma unroll
      for (int j = 0; j < 8; j++) o[j] = (bf16)tile[(kchunk * 8 + j) * 129 + n];
      *(bf16x8*)&dst[U * 8] = o;
    }
  } else {
    // cvt_pack_x: tile(mt,kc)=128x32, addr = kchunk*1024 + r*8 + kk
    int mt = blockIdx.x - 16, kc = blockIdx.y;
    int r = threadIdx.x >> 1;
    int khalf = threadIdx.x & 1;
    const float* src = x + (size_t)(mt * 128 + r) * 512 + kc * 32 + khalf * 16;
    float4 v0 = *(const float4*)(src + 0);
    float4 v1 = *(const float4*)(src + 4);
    float4 v2 = *(const float4*)(src + 8);
    float4 v3 = *(const float4*)(src + 12);
    bf16* dt = Xp + ((size_t)mt * 16 + kc) * 4096;
    bf16x8 a, b;
    a[0] = (bf16)v0.x; a[1] = (bf16)v0.y; a[2] = (bf16)v0.z; a[3] = (bf16)v0.w;
    a[4] = (bf16)v1.x; a[5] = (bf16)v1.y; a[6] = (bf16)v1.z; a[7] = (bf16)v1.w;
    b[0] = (bf16)v2.x; b[1] = (bf16)v2.y; b[2] = (bf16)v2.z; b[3] = (bf16)v2.w;
    b[4] = (bf16)v3.x; b[5] = (bf16)v3.y; b[6] = (bf16)v3.z; b[7] = (bf16)v3.w;
    int kc0 = khalf * 2;
    *(bf16x8*)&dt[(kc0 + 0) * 1024 + r * 8] = a;
    *(bf16x8*)&dt[(kc0 + 1) * 1024 + r * 8] = b;
  }
}

// ---------------------------------------------------------------------------
// QKV projection, 128x128 tiles. Grid (64 mt, 12 nt): nt 0-3 Q, 4-7 K,
// 8-11 V. A staged from packed bf16 Xp (pure 2xldg8 + 2xds_write, one-
// barrier dbuf); B-frags DIRECT coalesced ldg8 from L2-resident Wp1.
// Epilogue: LDS round-trip for coalesced 16B stores (Q/K rows [bh][n][d];
// V transposed to [bh][nb][d][n&63]). Q pre-scaled by 0.125*log2e.
// ---------------------------------------------------------------------------
__global__ __launch_bounds__(256, 3) void qkv_gemm(const bf16* __restrict__ Xp,
                                                   const bf16* __restrict__ Wp1,
                                                   const float* __restrict__ bqkv,
                                                   bf16* __restrict__ Q,
                                                   bf16* __restrict__ Kh,
                                                   bf16* __restrict__ Vt) {
  int mt = blockIdx.x, nt = blockIdx.y;
  int tid = threadIdx.x;
  int wave = tid >> 6, lane = tid & 63;
  int l16 = lane & 15, quad = lane >> 4;
  int wr = wave >> 1, wc = wave & 1;

  __shared__ __align__(16) bf16 SM[9216];  // A dbuf 2x4096; epilogue T 128x72

  const bf16* At = Xp + (size_t)mt * 16 * 4096;
  const bf16* Bt = Wp1 + (size_t)nt * 16 * 4096;

  bf16x8 pa0 = ldg8(At + tid * 8);
  bf16x8 pa1 = ldg8(At + 2048 + tid * 8);

  f32x4 acc[4][4] = {};
#pragma unroll 2
  for (int kc = 0; kc < 16; kc++) {
    bf16* A = SM + (kc & 1) * 4096;
    *(bf16x8*)&A[tid * 8] = pa0;
    *(bf16x8*)&A[2048 + tid * 8] = pa1;
    __syncthreads();
    if (kc < 15) {
      const bf16* an = At + (kc + 1) * 4096;
      pa0 = ldg8(an + tid * 8);
      pa1 = ldg8(an + 2048 + tid * 8);
    }
    bf16x8 af[4], bfr[4];
#pragma unroll
    for (int fi = 0; fi < 4; fi++)
      af[fi] = *(const bf16x8*)&A[(quad * 128 + wr * 64 + fi * 16 + l16) * 8];
    const bf16* Bk = Bt + kc * 4096;
#pragma unroll
    for (int fj = 0; fj < 4; fj++)
      bfr[fj] = ldg8(Bk + (quad * 128 + wc * 64 + fj * 16 + l16) * 8);
    __builtin_amdgcn_s_setprio(1);
#pragma unroll
    for (int fi = 0; fi < 4; fi++)
#pragma unroll
      for (int fj = 0; fj < 4; fj++)
        acc[fi][fj] = MFMA16(af[fi], bfr[fj], acc[fi][fj]);
    __builtin_amdgcn_s_setprio(0);
  }

  // ---- epilogue: LDS round-trip, coalesced 16B stores ----
  __syncthreads();  // all frag reads done before SM reuse
  const int TS = 72;
  int b = mt >> 5;

  if (nt < 8) {
    bool isQ = nt < 4;
    bf16* dstb = isQ ? Q : Kh;
    int hb = isQ ? nt * 2 : (nt - 4) * 2;
#pragma unroll
    for (int ph = 0; ph < 2; ph++) {
      if (wc == ph) {
#pragma unroll
        for (int fj = 0; fj < 4; fj++) {
          float bias = bqkv[nt * 128 + wc * 64 + fj * 16 + l16];
#pragma unroll
          for (int fi = 0; fi < 4; fi++)
#pragma unroll
            for (int rr = 0; rr < 4; rr++) {
              float v = acc[fi][fj][rr] + bias;
              if (isQ) v *= 0.18033688f;  // 0.125*log2e
              SM[(wr * 64 + fi * 16 + quad * 4 + rr) * TS + fj * 16 + l16] =
                  (bf16)v;
            }
        }
      }
      __syncthreads();
      int bh = b * 8 + hb + ph;
      bf16* dh = dstb + (size_t)bh * 4096 * 64 + (size_t)((mt & 31) * 128) * 64;
#pragma unroll
      for (int i = 0; i < 4; i++) {
        int U = tid + i * 256;
        int mr = U >> 3, oct = U & 7;
        bf16x8 v = ldg8(&SM[mr * TS + oct * 8]);
        *(bf16x8*)&dh[(size_t)mr * 64 + oct * 8] = v;
      }
      __syncthreads();
    }
  } else {
    int h0 = (nt - 8) * 2;
#pragma unroll
    for (int ph = 0; ph < 2; ph++) {
      if (wr == ph) {
#pragma unroll
        for (int fj = 0; fj < 4; fj++) {
          float bias = bqkv[nt * 128 + wc * 64 + fj * 16 + l16];
          int cp = wc * 64 + fj * 16 + l16;
#pragma unroll
          for (int fi = 0; fi < 4; fi++)
#pragma unroll
            for (int rr = 0; rr < 4; rr++)
              SM[cp * TS + fi * 16 + quad * 4 + rr] =
                  (bf16)(acc[fi][fj][rr] + bias);
        }
      }
      __syncthreads();
      int nb = (mt & 31) * 2 + ph;
#pragma unroll
      for (int i = 0; i < 4; i++) {
        int U = tid + i * 256;
        int cp = U >> 3, oct = U & 7;
        int h = h0 + (cp >> 6), d = cp & 63;
        int bh = b * 8 + h;
        bf16x8 v = ldg8(&SM[cp * TS + oct * 8]);
        *(bf16x8*)&Vt[(((size_t)bh * 64 + nb) * 64 + d) * 64 + oct * 8] = v;
      }
      __syncthreads();
    }
  }
}

// ---------------------------------------------------------------------------
// flash_partial (inner loop r2/r5/r7-proven, FROZEN): 1D grid 1024 with
// XCD-aware swizzle (T1): swz=(i&7)*128+(i>>3); l = half + 2*strip + 64*bh
// -> each XCD owns 2 bh entirely (K/V+Q working set 3MB < 4MB L2).
// 4 waves, 32 Q rows/wave, 32 KV-tiles of 64. Per-h2 clusters: QK(8 MFMA)
// -> SM -> PV+l(10 MFMA). In-reg P (cvt_pk+permlane), exp2, ones-MFMA
// rowsum. K/V dbuf, ONE barrier/tile, reg-prefetch after barrier.
// ---------------------------------------------------------------------------
__global__ __launch_bounds__(256, 4) void flash_partial(const bf16* __restrict__ Q,
                                                        const bf16* __restrict__ K,
                                                        const bf16* __restrict__ Vt,
                                                        bf16* __restrict__ Opart,
                                                        float* __restrict__ Lpart) {
  int i = blockIdx.x;
  int swz = (i & 7) * 128 + (i >> 3);  // bijective: 1024 % 8 == 0
  int half = swz & 1;
  int strip = (swz >> 1) & 31;
  int bh = swz >> 6;
  int tid = threadIdx.x;
  int wave = tid >> 6, lane = tid & 63;
  int l16 = lane & 15, quad = lane >> 4;

  const bf16* Qh = Q + (size_t)bh * 4096 * 64;
  const bf16* Kg = K + ((size_t)bh * 4096 + half * 2048) * 64;
  const bf16* Vg = Vt + (size_t)bh * 64 * 4096 + (size_t)half * 2048 * 64;

  __shared__ __align__(16) bf16 Klds[2][4096];
  __shared__ __align__(16) bf16 Vlds[2][4096];

  int qbase = strip * 128 + wave * 32;
  bf16x8 aq[2][2];
#pragma unroll
  for (int mt = 0; mt < 2; mt++) {
    const bf16* qr = Qh + (size_t)(qbase + mt * 16 + l16) * 64;
    aq[mt][0] = ldg8(qr + quad * 8);
    aq[mt][1] = ldg8(qr + 32 + quad * 8);
  }

  bf16x8 ones;
#pragma unroll
  for (int j = 0; j < 8; j++) ones[j] = (bf16)1.0f;

  f32x4 o[2][4] = {};
  f32x4 acc_l[2] = {};

  int e0 = tid * 8, e1 = (256 + tid) * 8;
  int r0 = e0 >> 6, r1 = e1 >> 6;
  int u0 = r0 * 8 + (((e0 & 63) >> 3) ^ (r0 & 7));
  int u1 = r1 * 8 + (((e1 & 63) >> 3) ^ (r1 & 7));

  bf16x8 kp0 = ldg8(Kg + e0), kp1 = ldg8(Kg + e1);
  bf16x8 vp0 = ldg8(Vg + e0), vp1 = ldg8(Vg + e1);

#pragma unroll 2
  for (int t = 0; t < 32; t++) {
    int cur = t & 1;
    bf16* kl = Klds[cur];
    bf16* vl = Vlds[cur];
    *(bf16x8*)&kl[u0 * 8] = kp0;
    *(bf16x8*)&kl[u1 * 8] = kp1;
    *(bf16x8*)&vl[u0 * 8] = vp0;
    *(bf16x8*)&vl[u1 * 8] = vp1;
    __syncthreads();

    if (t < 31) {
      const bf16* kg = Kg + (size_t)(t + 1) * 4096;
      const bf16* vg = Vg + (size_t)(t + 1) * 4096;
      kp0 = ldg8(kg + e0);
      kp1 = ldg8(kg + e1);
      vp0 = ldg8(vg + e0);
      vp1 = ldg8(vg + e1);
    }

#pragma unroll
    for (int h2 = 0; h2 < 2; h2++) {
      f32x4 s[2][2] = {};
      __builtin_amdgcn_s_setprio(1);
#pragma unroll
      for (int c2 = 0; c2 < 2; c2++) {
        int n = h2 * 32 + c2 * 16 + l16;
        bf16x8 k0 = *(const bf16x8*)&kl[(n * 8 + (quad ^ (n & 7))) * 8];
        bf16x8 k1 = *(const bf16x8*)&kl[(n * 8 + ((4 + quad) ^ (n & 7))) * 8];
#pragma unroll
        for (int mt = 0; mt < 2; mt++) {
          s[mt][c2] = MFMA16(k0, aq[mt][0], s[mt][c2]);
          s[mt][c2] = MFMA16(k1, aq[mt][1], s[mt][c2]);
        }
      }
      __builtin_amdgcn_s_setprio(0);

      bf16x8 pa[2];
#pragma unroll
      for (int mt = 0; mt < 2; mt++) {
        unsigned ue[2], wo[2];
#pragma unroll
        for (int c2 = 0; c2 < 2; c2++) {
          float p0 = __builtin_amdgcn_exp2f(s[mt][c2][0]);
          float p1 = __builtin_amdgcn_exp2f(s[mt][c2][1]);
          float p2 = __builtin_amdgcn_exp2f(s[mt][c2][2]);
          float p3 = __builtin_amdgcn_exp2f(s[mt][c2][3]);
          ue[c2] = cvt_pk_bf16(p0, p1);
          wo[c2] = cvt_pk_bf16(p2, p3);
        }
        pl32_swap(ue[0], ue[1]);
        pl16_swap(ue[0], ue[1]);
        pl32_swap(wo[0], wo[1]);
        pl16_swap(wo[0], wo[1]);
        u32x4 pk = {ue[0], wo[0], ue[1], wo[1]};
        pa[mt] = __builtin_bit_cast(bf16x8, pk);
      }

      __builtin_amdgcn_s_setprio(1);
      acc_l[0] = MFMA16(pa[0], ones, acc_l[0]);
      acc_l[1] = MFMA16(pa[1], ones, acc_l[1]);
#pragma unroll
      for (int ct = 0; ct < 4; ct++) {
        int d = ct * 16 + l16;
        bf16x8 bv = *(const bf16x8*)&vl[(d * 8 + ((h2 * 4 + quad) ^ (d & 7))) * 8];
        o[0][ct] = MFMA16(pa[0], bv, o[0][ct]);
        o[1][ct] = MFMA16(pa[1], bv, o[1][ct]);
      }
      __builtin_amdgcn_s_setprio(0);
    }
  }

  size_t ub = ((size_t)half * 16 + bh) * 32 + strip;
  bf16* op = Opart + ub * 8192;
#pragma unroll
  for (int mt = 0; mt < 2; mt++) {
#pragma unroll
    for (int ct = 0; ct < 4; ct++)
#pragma unroll
      for (int r = 0; r < 4; r++)
        op[(wave * 32 + mt * 16 + quad * 4 + r) * 64 + ct * 16 + l16] =
            (bf16)o[mt][ct][r];
    if (l16 == 0) {
#pragma unroll
      for (int r = 0; r < 4; r++)
        Lpart[ub * 128 + wave * 32 + mt * 16 + quad * 4 + r] = acc_l[mt][r];
    }
  }
}

// ---------------------------------------------------------------------------
// Output projection + FUSED combine (r8): 64x128 tiles, grid (128 mt, 4 nt)
// = 512 blocks = 2/CU. A-staging computes (o0+o1)/(l0+l1) from Opart/Lpart
// directly. B-frags direct ldg8 from Wp2.
// ---------------------------------------------------------------------------
__global__ __launch_bounds__(256, 4) void out_gemm(const bf16* __restrict__ Opart,
                                                   const float* __restrict__ Lpart,
                                                   const bf16* __restrict__ Wp2,
                                                   const float* __restrict__ bout,
                                                   float* __restrict__ Out) {
  int mt = blockIdx.x, nt = blockIdx.y;
  int tid = threadIdx.x;
  int wave = tid >> 6, lane = tid & 63;
  int l16 = lane & 15, quad = lane >> 4;
  int mt128 = mt >> 1, mhalf = mt & 1;
  int b = mt128 >> 5, strip = mt128 & 31;
  int r = mhalf * 64 + lane;

  __shared__ __align__(16) bf16 SM[2][2048];

  const bf16* Bt = Wp2 + (size_t)nt * 16 * 4096;

  bf16x8 po0, po1;
  float pls;
  {
    int h = 0, d0 = 0;  // kc = 0
    int bh = b * 8 + h;
    size_t s0 = ((size_t)bh * 32 + strip);
    size_t s1 = (((size_t)16 + bh) * 32 + strip);
    po0 = ldg8(&Opart[s0 * 8192 + r * 64 + d0 + wave * 8]);
    po1 = ldg8(&Opart[s1 * 8192 + r * 64 + d0 + wave * 8]);
    pls = Lpart[s0 * 128 + r] + Lpart[s1 * 128 + r];
  }

  f32x4 acc[4][2] = {};
#pragma unroll 2
  for (int kc = 0; kc < 16; kc++) {
    bf16* A = SM[kc & 1];
    float rl = 1.0f / pls;
    u32x4 pk = {
        cvt_pk_bf16(((float)po0[0] + (float)po1[0]) * rl,
                    ((float)po0[1] + (float)po1[1]) * rl),
        cvt_pk_bf16(((float)po0[2] + (float)po1[2]) * rl,
                    ((float)po0[3] + (float)po1[3]) * rl),
        cvt_pk_bf16(((float)po0[4] + (float)po1[4]) * rl,
                    ((float)po0[5] + (float)po1[5]) * rl),
        cvt_pk_bf16(((float)po0[6] + (float)po1[6]) * rl,
                    ((float)po0[7] + (float)po1[7]) * rl)};
    *(bf16x8*)&A[tid * 8] = __builtin_bit_cast(bf16x8, pk);
    __syncthreads();
    if (kc < 15) {
      int kn = kc + 1;
      int h = kn >> 1, d0 = (kn & 1) * 32;
      int bh = b * 8 + h;
      size_t s0 = ((size_t)bh * 32 + strip);
      size_t s1 = (((size_t)16 + bh) * 32 + strip);
      po0 = ldg8(&Opart[s0 * 8192 + r * 64 + d0 + wave * 8]);
      po1 = ldg8(&Opart[s1 * 8192 + r * 64 + d0 + wave * 8]);
      pls = Lpart[s0 * 128 + r] + Lpart[s1 * 128 + r];
    }
    bf16x8 af[4], bfr[2];
#pragma unroll
    for (int fi = 0; fi < 4; fi++)
      af[fi] = *(const bf16x8*)&A[(quad * 64 + fi * 16 + l16) * 8];
    const bf16* Bk = Bt + kc * 4096;
#pragma unroll
    for (int fj = 0; fj < 2; fj++)
      bfr[fj] = ldg8(Bk + (quad * 128 + wave * 32 + fj * 16 + l16) * 8);
    __builtin_amdgcn_s_setprio(1);
#pragma unroll
    for (int fi = 0; fi < 4; fi++)
#pragma unroll
      for (int fj = 0; fj < 2; fj++)
        acc[fi][fj] = MFMA16(af[fi], bfr[fj], acc[fi][fj]);
    __builtin_amdgcn_s_setprio(0);
  }

#pragma unroll
  for (int fj = 0; fj < 2; fj++) {
    int c = nt * 128 + wave * 32 + fj * 16 + l16;
    float bias = bout[c];
#pragma unroll
    for (int fi = 0; fi < 4; fi++) {
#pragma unroll
      for (int rr = 0; rr < 4; rr++) {
        int m = mt * 64 + fi * 16 + quad * 4 + rr;
        Out[(size_t)m * 512 + c] = acc[fi][fj][rr] + bias;
      }
    }
  }
}

// ---------------------------------------------------------------------------
// ws layout (no overlays; end 52,953,088 < 61.4MB):
//   Q 0 (8.39M) | K 8388608 | Vt 16777216 | Wp2 25165824 (0.52M) |
//   Opart 25690112 (16.78M) | Lpart 42467328 (0.52M) | Wp1 42991616 (1.57M)
//   | Xp 44564480 (8.39M)
// ---------------------------------------------------------------------------
extern "C" void kernel_launch(void* const* d_in, const int* in_sizes, int n_in,
                              void* d_out, int out_size, void* d_ws,
                              size_t ws_size, hipStream_t stream) {
  const float* x = (const float*)d_in[0];
  const float* w_qkv = (const float*)d_in[1];
  const float* b_qkv = (const float*)d_in[2];
  const float* w_out = (const float*)d_in[3];
  const float* b_out = (const float*)d_in[4];
  float* out = (float*)d_out;

  char* ws = (char*)d_ws;
  bf16* Q = (bf16*)(ws + 0);
  bf16* K = (bf16*)(ws + 8388608);
  bf16* Vt = (bf16*)(ws + 16777216);
  bf16* Wp2 = (bf16*)(ws + 25165824);
  bf16* Opart = (bf16*)(ws + 25690112);
  float* Lpart = (float*)(ws + 42467328);
  bf16* Wp1 = (bf16*)(ws + 42991616);
  bf16* Xp = (bf16*)(ws + 44564480);

  prep<<<dim3(80, 16), 256, 0, stream>>>(w_qkv, w_out, x, Wp1, Wp2, Xp);
  qkv_gemm<<<dim3(64, 12), 256, 0, stream>>>(Xp, Wp1, b_qkv, Q, K, Vt);
  flash_partial<<<dim3(1024), 256, 0, stream>>>(Q, K, Vt, Opart, Lpart);
  out_gemm<<<dim3(128, 4), 256, 0, stream>>>(Opart, Lpart, Wp2, b_out, out);
}